// Round 13
// baseline (193.693 us; speedup 1.0000x reference)
//
#include <hip/hip_runtime.h>
#include <hip/hip_bf16.h>
#include <math.h>

#define NH 12
#define HD 64
#define NSEQ 1024
#define DMODEL 768
#define LOG2E 1.44269504f

#if defined(__has_builtin)
#if __has_builtin(__builtin_amdgcn_exp2f)
#define EXP2R(x) __builtin_amdgcn_exp2f(x)
#endif
#endif
#ifndef EXP2R
#define EXP2R(x) exp2f(x)
#endif

typedef unsigned short ushort_t;
typedef float f32x4 __attribute__((ext_vector_type(4)));
typedef short bf16x8 __attribute__((ext_vector_type(8)));

__device__ __forceinline__ ushort_t f2bf(float f) {
    unsigned int u = __float_as_uint(f);
    u += 0x7FFFu + ((u >> 16) & 1u);   // RNE
    return (ushort_t)(u >> 16);
}

__device__ __forceinline__ unsigned pk2(float x, float y) {
    __hip_bfloat162 t = __float22bfloat162_rn(make_float2(x, y));
    union { __hip_bfloat162 b; unsigned u; } c; c.b = t;
    return c.u;
}

// async global->LDS DMA, 16B per lane; LDS dest = wave-uniform base + lane*16
__device__ __forceinline__ void gl_lds16(const ushort_t* g, ushort_t* l) {
    __builtin_amdgcn_global_load_lds(
        (const __attribute__((address_space(1))) unsigned int*)g,
        (__attribute__((address_space(3))) unsigned int*)l, 16, 0, 0);
}

// ---------------------------------------------------------------------------
// prep kernel (R12 structure): x + qkv_w fp32->bf16 only.
// ---------------------------------------------------------------------------
#define XB_N   3145728u
#define WQB_N  1769472u
#define PWB_N  589824u
#define CVT_BLOCKS 2400

__global__ __launch_bounds__(256) void prep_kernel(
    const float* __restrict__ x, const float* __restrict__ w1,
    ushort_t* __restrict__ dst)
{
    const int t = threadIdx.x;
    const unsigned i = blockIdx.x * 256 + t;      // 8-elem chunk id
    const unsigned n0 = XB_N / 8, n1 = n0 + WQB_N / 8;
    if (i >= n1) return;
    const float* src; unsigned off;
    if (i < n0) { src = x;  off = i; }
    else        { src = w1; off = i - n0; }
    const float4 a = ((const float4*)src)[off * 2];
    const float4 b = ((const float4*)src)[off * 2 + 1];
    uint4 pk;
    pk.x = pk2(a.x, a.y); pk.y = pk2(a.z, a.w);
    pk.z = pk2(b.x, b.y); pk.w = pk2(b.z, b.w);
    ((uint4*)dst)[i] = pk;
}

__device__ __forceinline__ int bucketf(int rel) {
    const int n = -rel;
    const int u = (n < 0) ? 16 : 0;
    const int a = n < 0 ? -n : n;
    if (a < 8) return u + a;
    int v = 8 + (int)(log2f((float)a * 0.125f) * 2.0f + 1e-4f);
    if (v > 15) v = 15;
    return u + v;
}

// ---------------------------------------------------------------------------
// QKV GEMM dispatch (R12 structure, unchanged): GEMM + LUT pack + pw cvt.
// ---------------------------------------------------------------------------
#define QKV_BLOCKS 576
#define PACK_BLOCKS 4096
#define PW_BLOCKS 288

__global__ __launch_bounds__(256) void qkv_gemm(
    const ushort_t* __restrict__ A, const ushort_t* __restrict__ B,
    const float* __restrict__ bias,
    ushort_t* __restrict__ Qb, ushort_t* __restrict__ Kb, ushort_t* __restrict__ Vtb,
    const float* __restrict__ coords, const float* __restrict__ elev,
    const float* __restrict__ alpha_p, unsigned* __restrict__ pack,
    const float* __restrict__ pw, ushort_t* __restrict__ pwb)
{
    // dbuf layout (ushort idx): As(b) @ b*16384, Bs(b) @ b*16384 + 8192
    __shared__ __align__(16) ushort_t SM[32768];
    const int t = threadIdx.x;

    if (blockIdx.x >= QKV_BLOCKS + PACK_BLOCKS) {
        // ---- proj_w conversion tail ----
        const unsigned i = (blockIdx.x - QKV_BLOCKS - PACK_BLOCKS) * 256 + t;
        if (i >= PWB_N / 8) return;
        const float4 a = ((const float4*)pw)[i * 2];
        const float4 b = ((const float4*)pw)[i * 2 + 1];
        uint4 pk;
        pk.x = pk2(a.x, a.y); pk.y = pk2(a.z, a.w);
        pk.z = pk2(b.x, b.y); pk.w = pk2(b.z, b.w);
        ((uint4*)pwb)[i] = pk;
        return;
    }
    if (blockIdx.x >= QKV_BLOCKS) {
        // ---- bias-pack half (LUT in SM bytes) ----
        unsigned char* LUT = (unsigned char*)SM;
        LUT[t] = (unsigned char)bucketf(t - 128);
        if (t == 0) LUT[256] = (unsigned char)bucketf(128);
        __syncthreads();

        const int blk = blockIdx.x - QKV_BLOCKS;
        const int b = blk >> 10, i = blk & 1023;
        const float alpha = alpha_p[0];
        const float2 ci = *(const float2*)&coords[(size_t)(b * NSEQ + i) * 2];
        const int cxi = (int)(ci.x * 128.0f), cyi = (int)(ci.y * 128.0f);
        const float ei = elev[b * NSEQ + i];
        const int j0 = t * 4;
        const float4 c01 = *(const float4*)&coords[(size_t)(b * NSEQ + j0) * 2];
        const float4 c23 = *(const float4*)&coords[(size_t)(b * NSEQ + j0 + 2) * 2];
        const float4 ej4 = *(const float4*)&elev[b * NSEQ + j0];
        const float cjx[4] = {c01.x, c01.z, c23.x, c23.z};
        const float cjy[4] = {c01.y, c01.w, c23.y, c23.w};
        const float ejv[4] = {ej4.x, ej4.y, ej4.z, ej4.w};
        unsigned r[4];
        #pragma unroll
        for (int k = 0; k < 4; ++k) {
            const int dx = cxi - (int)(cjx[k] * 128.0f);
            const int dy = cyi - (int)(cjy[k] * 128.0f);
            const int idx = ((int)LUT[dx + 128] << 5) | (int)LUT[dy + 128];
            const float ed = (ejv[k] - ei) * 1e-3f;
            const float eb = fmaxf(-alpha * fmaxf(ed, 0.0f), -10.0f) * LOG2E;
            r[k] = ((unsigned)f2bf(eb) << 16) | (unsigned)idx;
        }
        uint4 o; o.x = r[0]; o.y = r[1]; o.z = r[2]; o.w = r[3];
        *(uint4*)&pack[((size_t)b << 20) + (size_t)i * NSEQ + j0] = o;
        return;
    }

    // ---- GEMM half ----
    // XCD swizzle: 576 = 8 XCDs x 72; each XCD owns 4 complete M-panels.
    const int lid = (blockIdx.x & 7) * 72 + (blockIdx.x >> 3);
    const int bx = lid % 18, by = lid / 18;
    const int m0 = by * 128, c0 = bx * 128;

    const int lane = t & 63, w = t >> 6;
    const int wr = w >> 1, wc = w & 1;            // wave quadrant: 64M x 64N
    const int col = lane & 15, quad = lane >> 4;
    const int c7 = col & 7;

    const f32x4 zero = {0.f, 0.f, 0.f, 0.f};
    f32x4 acc[4][4];
    #pragma unroll
    for (int i = 0; i < 4; ++i)
        #pragma unroll
        for (int j = 0; j < 4; ++j) acc[i][j] = zero;

    // staging: wave w stages rows w*32..w*32+31 of A and B (4 gl_lds each).
    // source col pre-swizzled so LDS (row, g) holds global group g^(row&7).
    const int r8 = lane >> 3, g8 = lane & 7;
    const int gsw = ((g8 ^ r8) * 8);
    const ushort_t* Ag = A + (size_t)(m0 + w * 32 + r8) * DMODEL + gsw;
    const ushort_t* Bg = B + (size_t)(c0 + w * 32 + r8) * DMODEL + gsw;
    const int wso = (w * 32) * 64;                // wave staging offset in buf

    auto STAGE = [&](int bo, int k0) {
        ushort_t* Aw = SM + bo + wso;
        ushort_t* Bw = SM + bo + 8192 + wso;
        gl_lds16(Ag + k0, Aw);
        gl_lds16(Ag + (size_t)8 * DMODEL + k0, Aw + 8 * 64);
        gl_lds16(Ag + (size_t)16 * DMODEL + k0, Aw + 16 * 64);
        gl_lds16(Ag + (size_t)24 * DMODEL + k0, Aw + 24 * 64);
        gl_lds16(Bg + k0, Bw);
        gl_lds16(Bg + (size_t)8 * DMODEL + k0, Bw + 8 * 64);
        gl_lds16(Bg + (size_t)16 * DMODEL + k0, Bw + 16 * 64);
        gl_lds16(Bg + (size_t)24 * DMODEL + k0, Bw + 24 * 64);
    };

    STAGE(0, 0);
    __syncthreads();   // prologue drain: buf0 ready

    #pragma unroll 2
    for (int k = 0; k < 12; ++k) {
        const int bo = (k & 1) * 16384;
        if (k < 11) STAGE(16384 - bo, (k + 1) * 64);   // issue next (no wait)
        #pragma unroll
        for (int kk = 0; kk < 2; ++kk) {
            bf16x8 af[4], bf[4];
            #pragma unroll
            for (int im = 0; im < 4; ++im)
                af[im] = *(const bf16x8*)&SM[bo + (wr * 64 + im * 16 + col) * 64
                        + ((4 * kk + quad) ^ c7) * 8];
            #pragma unroll
            for (int jn = 0; jn < 4; ++jn)
                bf[jn] = *(const bf16x8*)&SM[bo + 8192 + (wc * 64 + jn * 16 + col) * 64
                        + ((4 * kk + quad) ^ c7) * 8];
            #pragma unroll
            for (int im = 0; im < 4; ++im)
                #pragma unroll
                for (int jn = 0; jn < 4; ++jn)
                    acc[im][jn] = __builtin_amdgcn_mfma_f32_16x16x32_bf16(af[im], bf[jn], acc[im][jn], 0, 0, 0);
        }
        __syncthreads();   // ONE barrier/step; vmcnt drain lands after compute
    }

    const int cbw = c0 + wc * 64;                 // wave's 64-col base = one head
    const int s = cbw / DMODEL;                   // wave-uniform
    const int h = (cbw % DMODEL) >> 6;
    const int b = m0 >> 10;
    const int bh = b * NH + h;
    const int n0 = (m0 & (NSEQ - 1)) + wr * 64;

    float bv[4];
    #pragma unroll
    for (int jn = 0; jn < 4; ++jn) bv[jn] = bias[cbw + jn * 16 + col];

    if (s < 2) {
        // LDS transpose epilogue: per im-block the wave writes a 16x64 bf16
        // tile (stride 72), reads rows back, stores 2 coalesced uint4/lane.
        ushort_t* lt = SM + w * 1152;             // 16 rows x 72
        ushort_t* dst = (s == 0) ? Qb : Kb;
        const float sc = (s == 0) ? 0.125f * LOG2E : 1.0f;
        const int row16 = lane >> 2, seg = lane & 3;
        #pragma unroll
        for (int im = 0; im < 4; ++im) {
            #pragma unroll
            for (int jn = 0; jn < 4; ++jn) {
                const f32x4 a = acc[im][jn];
                #pragma unroll
                for (int r = 0; r < 4; ++r)
                    lt[(quad * 4 + r) * 72 + jn * 16 + col] = f2bf((a[r] + bv[jn]) * sc);
            }
            // same-wave DS is in-order: reads below see the writes above
            const uint4 u0 = *(const uint4*)&lt[row16 * 72 + seg * 8];
            const uint4 u1 = *(const uint4*)&lt[row16 * 72 + 32 + seg * 8];
            const size_t gb = ((size_t)bh * NSEQ + n0 + im * 16 + row16) * HD
                            + seg * 8;
            *(uint4*)&dst[gb] = u0;
            *(uint4*)&dst[gb + 32] = u1;
        }
    } else {
        #pragma unroll
        for (int im = 0; im < 4; ++im) {
            #pragma unroll
            for (int jn = 0; jn < 4; ++jn) {
                const int d = jn * 16 + col;
                const float bvv = bv[jn];
                const f32x4 a = acc[im][jn];
                uint2 p;
                p.x = pk2(a[0] + bvv, a[1] + bvv);
                p.y = pk2(a[2] + bvv, a[3] + bvv);
                *(uint2*)&Vtb[((size_t)bh * HD + d) * NSEQ + n0 + im * 16 + quad * 4] = p;
            }
        }
    }
}

// ---------------------------------------------------------------------------
// Fused flash attention, R13: 512 threads / 8 waves, TWO Q-tiles of the
// SAME (b,h) per block sharing one K/V double-buffer. Waves 0-3 own Q-tile
// i0, waves 4-7 own Q-tile i0+64; all 8 iterate the same KV sequence, so
// K/V staging per Q-row halves and the per-tile barrier drain amortizes
// over 2x MFMA work. Grid 384 = all blocks co-resident (2/CU), no tail.
// Unlike R3's failed split: no partial-sum combine, no duplicated K/V LDS.
// Per-wave math identical to R12 (gl_lds swizzle, raw v_exp, f32 table,
// bias prefetch pipeline, setprio).
// ---------------------------------------------------------------------------
#define RBIAS32(u) (tabu32[(u) & 1023u] + __uint_as_float((u) & 0xFFFF0000u))

__global__ __launch_bounds__(512) void attn_mfma(
    const ushort_t* __restrict__ Qb, const ushort_t* __restrict__ Kb,
    const ushort_t* __restrict__ Vtb,
    const unsigned* __restrict__ pack,
    const float* __restrict__ table,
    ushort_t* __restrict__ Ob)
{
    __shared__ __align__(16) ushort_t Ks[2][64 * 64];
    __shared__ __align__(16) ushort_t Vt[2][64 * 64];
    __shared__ __align__(16) ushort_t Ps[128 * 72];
    __shared__ float tabu32[1024];   // table[:,h] * log2e (f32)

    const int t = threadIdx.x;
    const int lane = t & 63, w = t >> 6;          // 8 waves
    const int grp = w >> 2, wg = w & 3;           // Q-tile group, wave-in-group
    const int col = lane & 15, quad = lane >> 4;
    const int c7 = col & 7;
    const int bid = (blockIdx.x & 7) * 48 + (blockIdx.x >> 3);   // XCD swizzle (384=8x48)
    const int it2 = bid & 7, bh = bid >> 3;
    const int h = bh % NH, b = bh / NH;
    const int i0 = it2 * 128 + grp * 64;          // this wave-group's Q-tile

    for (int i = t; i < 1024; i += 512)
        tabu32[i] = table[i * NH + h] * LOG2E;

    const ushort_t* Qg = Qb + ((size_t)bh * NSEQ + i0 + wg * 16 + col) * HD;
    const bf16x8 aq0 = *(const bf16x8*)(Qg + quad * 8);
    const bf16x8 aq1 = *(const bf16x8*)(Qg + 32 + quad * 8);

    const size_t kvbase = (size_t)bh * NSEQ * HD;
    const unsigned* prow = pack + ((size_t)b << 20)
                         + (size_t)(i0 + wg * 16 + col) * NSEQ + quad * 4;

    // gl_lds staging: wave w stages rows 8w..8w+7 of K and of V^T (1 gl_lds
    // each; 8 waves cover 64 rows). Source group pre-swizzled by lg^lr so
    // LDS (row, pos) holds global group pos^(row&7)  (8w = 0 mod 8).
    const int lr = lane >> 3, lg = lane & 7;
    const int swz = (lg ^ lr) * 8;
    const int row0 = 8 * w + lr;
    const ushort_t* Kg = Kb + kvbase + (size_t)row0 * HD + swz;
    const ushort_t* Vg = Vtb + kvbase + (size_t)row0 * NSEQ + swz;
    const int kvso = (8 * w) * 64;                // wave LDS base (ushorts)

    auto STAGE_KV = [&](int buf, int j0) {
        gl_lds16(Kg + (size_t)j0 * HD, &Ks[buf][kvso]);
        gl_lds16(Vg + j0, &Vt[buf][kvso]);
    };

    STAGE_KV(0, 0);

    // bias pipeline: pk4g = pack words for the tile to gather next;
    // pk4l = loads in flight two tiles ahead; rbc = bias for current tile.
    uint4 pk4g[4], pk4l[4];
    #pragma unroll
    for (int jb = 0; jb < 4; ++jb)
        pk4g[jb] = *(const uint4*)(prow + jb * 16);

    __syncthreads();   // drains tabu32 writes AND the buf0 DMA

    float rbc[4][4], rbn[4][4];
    #pragma unroll
    for (int jb = 0; jb < 4; ++jb) {
        const uint4 pkv = pk4g[jb];
        rbc[jb][0] = RBIAS32(pkv.x);
        rbc[jb][1] = RBIAS32(pkv.y);
        rbc[jb][2] = RBIAS32(pkv.z);
        rbc[jb][3] = RBIAS32(pkv.w);
    }
    #pragma unroll
    for (int jb = 0; jb < 4; ++jb)
        pk4g[jb] = *(const uint4*)(prow + 64 + jb * 16);

    const f32x4 zero = {0.f, 0.f, 0.f, 0.f};
    f32x4 o_acc[4];
    #pragma unroll
    for (int i = 0; i < 4; ++i) o_acc[i] = zero;
    float l_l = 0.f;

    const int kx = (quad ^ c7) * 8;               // swizzled group offset

    #pragma unroll 2
    for (int jt = 0; jt < 16; ++jt) {
        if (jt) __syncthreads();   // buf[cur] DMA drained; buf[cur^1] reads done
        const int cur = jt & 1;

        if (jt < 15) STAGE_KV(cur ^ 1, (jt + 1) * 64);   // DMA next tile
        if (jt < 14) {
            const int j2 = (jt + 2) * 64;
            #pragma unroll
            for (int jb = 0; jb < 4; ++jb)
                pk4l[jb] = *(const uint4*)(prow + j2 + jb * 16);
        }

        // S^T = K Q^T  (swizzled fragment reads: group g at pos g^(row&7))
        f32x4 sacc[4];
        __builtin_amdgcn_s_setprio(1);
        #pragma unroll
        for (int jb = 0; jb < 4; ++jb) {
            sacc[jb] = zero;
            const bf16x8 kb0 = *(const bf16x8*)&Ks[cur][(jb * 16 + col) * 64 + kx];
            const bf16x8 kb1 = *(const bf16x8*)&Ks[cur][(jb * 16 + col) * 64 + (kx ^ 32)];
            sacc[jb] = __builtin_amdgcn_mfma_f32_16x16x32_bf16(kb0, aq0, sacc[jb], 0, 0, 0);
            sacc[jb] = __builtin_amdgcn_mfma_f32_16x16x32_bf16(kb1, aq1, sacc[jb], 0, 0, 0);
        }
        __builtin_amdgcn_s_setprio(0);

        // fixed-m softmax with PREFETCHED bias: p = exp2(s + rbc), raw v_exp
        float psum = 0.f;
        #pragma unroll
        for (int jb = 0; jb < 4; ++jb) {
            const float p0 = EXP2R(sacc[jb][0] + rbc[jb][0]);
            const float p1 = EXP2R(sacc[jb][1] + rbc[jb][1]);
            const float p2 = EXP2R(sacc[jb][2] + rbc[jb][2]);
            const float p3 = EXP2R(sacc[jb][3] + rbc[jb][3]);
            psum += (p0 + p1) + (p2 + p3);
            uint2 st;
            st.x = pk2(p0, p1);
            st.y = pk2(p2, p3);
            *(uint2*)&Ps[(w * 16 + col) * 72 + jb * 16 + quad * 4] = st;
        }
        l_l += psum;

        // O += P V; next-tile bias gathers interleaved with the PV MFMAs
        const bf16x8 ap0 = *(const bf16x8*)&Ps[(w * 16 + col) * 72 + quad * 8];
        const bf16x8 ap1 = *(const bf16x8*)&Ps[(w * 16 + col) * 72 + 32 + quad * 8];
        __builtin_amdgcn_s_setprio(1);
        #pragma unroll
        for (int db = 0; db < 4; ++db) {
            const bf16x8 vv0 = *(const bf16x8*)&Vt[cur][(db * 16 + col) * 64 + kx];
            const bf16x8 vv1 = *(const bf16x8*)&Vt[cur][(db * 16 + col) * 64 + (kx ^ 32)];
            o_acc[db] = __builtin_amdgcn_mfma_f32_16x16x32_bf16(ap0, vv0, o_acc[db], 0, 0, 0);
            o_acc[db] = __builtin_amdgcn_mfma_f32_16x16x32_bf16(ap1, vv1, o_acc[db], 0, 0, 0);
            if (jt < 15) {
                const uint4 pkv = pk4g[db];
                rbn[db][0] = RBIAS32(pkv.x);
                rbn[db][1] = RBIAS32(pkv.y);
                rbn[db][2] = RBIAS32(pkv.z);
                rbn[db][3] = RBIAS32(pkv.w);
            }
        }
        __builtin_amdgcn_s_setprio(0);

        // rotate pipeline regs (renamed away by the unroll)
        #pragma unroll
        for (int jb = 0; jb < 4; ++jb) {
            pk4g[jb] = pk4l[jb];
            rbc[jb][0] = rbn[jb][0];
            rbc[jb][1] = rbn[jb][1];
            rbc[jb][2] = rbn[jb][2];
            rbc[jb][3] = rbn[jb][3];
        }
    }

    // epilogue: reduce l over quads, normalize, store bf16
    float l = l_l;
    l += __shfl_xor(l, 16);
    l += __shfl_xor(l, 32);
    #pragma unroll
    for (int r = 0; r < 4; ++r) {
        const float lr2 = __shfl(l, wg * 16 + quad * 4 + r);   // lane with col=quad*4+r
        const float inv = 1.f / lr2;
        const int ri = wg * 16 + quad * 4 + r;
        const size_t base = ((size_t)(b * NSEQ) + i0 + ri) * DMODEL + h * HD;
        #pragma unroll
        for (int db = 0; db < 4; ++db)
            Ob[base + db * 16 + col] = f2bf(o_acc[db][r] * inv);
    }
}

// ---------------------------------------------------------------------------
// Proj GEMM (R8 structure, unchanged): 64x64 tiles, BK=64, 2-phase dbuf.
// ---------------------------------------------------------------------------
__global__ __launch_bounds__(256) void proj_gemm(
    const ushort_t* __restrict__ A, const ushort_t* __restrict__ B,
    const float* __restrict__ bias, float* __restrict__ out)
{
    // dbuf layout (ushort idx): As(b) @ b*8192, Bs(b) @ b*8192 + 4096
    __shared__ __align__(16) ushort_t SM[16384];
    const int t = threadIdx.x;
    const int lane = t & 63, w = t >> 6;
    const int wr = w >> 1, wc = w & 1;
    const int col = lane & 15, quad = lane >> 4;
    const int c7 = col & 7;
    const int m0 = blockIdx.y * 64, c0 = blockIdx.x * 64;

    const f32x4 zero = {0.f, 0.f, 0.f, 0.f};
    f32x4 acc[2][2];
    #pragma unroll
    for (int i = 0; i < 2; ++i)
        #pragma unroll
        for (int j = 0; j < 2; ++j) acc[i][j] = zero;

    const int r8 = lane >> 3, g8 = lane & 7;
    const int gsw = ((g8 ^ r8) * 8);
    const ushort_t* Ag = A + (size_t)(m0 + w * 16 + r8) * DMODEL + gsw;
    const ushort_t* Bg = B + (size_t)(c0 + w * 16 + r8) * DMODEL + gsw;
    const int wso = (w * 16) * 64;

    auto STAGE = [&](int bo, int k0) {
        ushort_t* Aw = SM + bo + wso;
        ushort_t* Bw = SM + bo + 4096 + wso;
        gl_lds16(Ag + k0, Aw);
        gl_lds16(Ag + (size_t)8 * DMODEL + k0, Aw + 8 * 64);
        gl_lds16(Bg + k0, Bw);
        gl_lds16(Bg + (size_t)8 * DMODEL + k0, Bw + 8 * 64);
    };

    STAGE(0, 0);
    __syncthreads();

    #pragma unroll 2
    for (int k = 0; k < 12; ++k) {
        const int bo = (k & 1) * 8192;
        if (k < 11) STAGE(8192 - bo, (k + 1) * 64);
        #pragma unroll
        for (int kk = 0; kk < 2; ++kk) {
            bf16x8 af[2], bf[2];
            #pragma unroll
            for (int im = 0; im < 2; ++im)
                af[im] = *(const bf16x8*)&SM[bo + (wr * 32 + im * 16 + col) * 64
                        + ((4 * kk + quad) ^ c7) * 8];
            #pragma unroll
            for (int jn = 0; jn < 2; ++jn)
                bf[jn] = *(const bf16x8*)&SM[bo + 4096 + (wc * 32 + jn * 16 + col) * 64
                        + ((4 * kk + quad) ^ c7) * 8];
            #pragma unroll
            for (int im = 0; im < 2; ++im)
                #pragma unroll
                for (int jn = 0; jn < 2; ++jn)
                    acc[im][jn] = __builtin_amdgcn_mfma_f32_16x16x32_bf16(af[im], bf[jn], acc[im][jn], 0, 0, 0);
        }
        __syncthreads();
    }

    #pragma unroll
    for (int im = 0; im < 2; ++im) {
        #pragma unroll
        for (int jn = 0; jn < 2; ++jn) {
            const int c = c0 + wc * 32 + jn * 16 + col;
            const float bv = bias[c];
            #pragma unroll
            for (int r = 0; r < 4; ++r) {
                const int m = m0 + wr * 32 + im * 16 + quad * 4 + r;
                out[(size_t)m * DMODEL + c] = acc[im][jn][r] + bv;
            }
        }
    }
}

extern "C" void kernel_launch(void* const* d_in, const int* in_sizes, int n_in,
                              void* d_out, int out_size, void* d_ws, size_t ws_size,
                              hipStream_t stream) {
    const float* x       = (const float*)d_in[0];
    const float* coords  = (const float*)d_in[1];
    const float* elev    = (const float*)d_in[2];
    const float* qkv_w   = (const float*)d_in[3];
    const float* qkv_b   = (const float*)d_in[4];
    const float* proj_w  = (const float*)d_in[5];
    const float* proj_b  = (const float*)d_in[6];
    const float* btable  = (const float*)d_in[7];
    const float* alpha   = (const float*)d_in[8];
    float* out = (float*)d_out;

    ushort_t* wsu = (ushort_t*)d_ws;
    ushort_t* xb  = wsu;
    ushort_t* wqb = wsu + 3145728;
    ushort_t* pwb = wsu + 4915200;
    ushort_t* Qb  = wsu + 5505024;
    ushort_t* Kb  = wsu + 8650752;
    ushort_t* Vtb = wsu + 11796480;
    ushort_t* Ob  = wsu + 14942208;
    unsigned* pck = (unsigned*)(wsu + 18087936);   // 4M uint32 = 16 MB

    prep_kernel<<<CVT_BLOCKS, 256, 0, stream>>>(x, qkv_w, wsu);
    qkv_gemm<<<QKV_BLOCKS + PACK_BLOCKS + PW_BLOCKS, 256, 0, stream>>>(
        xb, wqb, qkv_b, Qb, Kb, Vtb, coords, elev, alpha, pck, proj_w, pwb);
    attn_mfma<<<384, 512, 0, stream>>>(Qb, Kb, Vtb, pck, btable, Ob);
    proj_gemm<<<dim3(12, 64), 256, 0, stream>>>(Ob, pwb, proj_b, out);
}

// Round 14
// 162.765 us; speedup vs baseline: 1.1900x; 1.1900x over previous
//
#include <hip/hip_runtime.h>
#include <hip/hip_bf16.h>
#include <math.h>

#define NH 12
#define HD 64
#define NSEQ 1024
#define DMODEL 768
#define LOG2E 1.44269504f

#if defined(__has_builtin)
#if __has_builtin(__builtin_amdgcn_exp2f)
#define EXP2R(x) __builtin_amdgcn_exp2f(x)
#endif
#endif
#ifndef EXP2R
#define EXP2R(x) exp2f(x)
#endif

typedef unsigned short ushort_t;
typedef float f32x4 __attribute__((ext_vector_type(4)));
typedef short bf16x8 __attribute__((ext_vector_type(8)));

__device__ __forceinline__ ushort_t f2bf(float f) {
    unsigned int u = __float_as_uint(f);
    u += 0x7FFFu + ((u >> 16) & 1u);   // RNE
    return (ushort_t)(u >> 16);
}

__device__ __forceinline__ unsigned pk2(float x, float y) {
    __hip_bfloat162 t = __float22bfloat162_rn(make_float2(x, y));
    union { __hip_bfloat162 b; unsigned u; } c; c.b = t;
    return c.u;
}

// async global->LDS DMA, 16B per lane; LDS dest = wave-uniform base + lane*16
__device__ __forceinline__ void gl_lds16(const ushort_t* g, ushort_t* l) {
    __builtin_amdgcn_global_load_lds(
        (const __attribute__((address_space(1))) unsigned int*)g,
        (__attribute__((address_space(3))) unsigned int*)l, 16, 0, 0);
}

// ---------------------------------------------------------------------------
// prep kernel (R12 structure): x + qkv_w fp32->bf16 only. pack + proj_w cvt
// live in the qkv dispatch (fused layout measured best: tail backfill +
// one fewer launch gap).
// ---------------------------------------------------------------------------
#define XB_N   3145728u
#define WQB_N  1769472u
#define PWB_N  589824u
#define CVT_BLOCKS 2400

__global__ __launch_bounds__(256) void prep_kernel(
    const float* __restrict__ x, const float* __restrict__ w1,
    ushort_t* __restrict__ dst)
{
    const int t = threadIdx.x;
    const unsigned i = blockIdx.x * 256 + t;      // 8-elem chunk id
    const unsigned n0 = XB_N / 8, n1 = n0 + WQB_N / 8;
    if (i >= n1) return;
    const float* src; unsigned off;
    if (i < n0) { src = x;  off = i; }
    else        { src = w1; off = i - n0; }
    const float4 a = ((const float4*)src)[off * 2];
    const float4 b = ((const float4*)src)[off * 2 + 1];
    uint4 pk;
    pk.x = pk2(a.x, a.y); pk.y = pk2(a.z, a.w);
    pk.z = pk2(b.x, b.y); pk.w = pk2(b.z, b.w);
    ((uint4*)dst)[i] = pk;
}

__device__ __forceinline__ int bucketf(int rel) {
    const int n = -rel;
    const int u = (n < 0) ? 16 : 0;
    const int a = n < 0 ? -n : n;
    if (a < 8) return u + a;
    int v = 8 + (int)(log2f((float)a * 0.125f) * 2.0f + 1e-4f);
    if (v > 15) v = 15;
    return u + v;
}

// ---------------------------------------------------------------------------
// QKV GEMM dispatch (R12): blocks [0,576) GEMM (128x128, BK=64, 2-phase
// dbuf, both-sides XOR swizzle, XCD swizzle); [576,4672) LUT bias-pack;
// [4672,4960) proj_w cvt. Pack/pw blocks backfill the GEMM tail.
// ---------------------------------------------------------------------------
#define QKV_BLOCKS 576
#define PACK_BLOCKS 4096
#define PW_BLOCKS 288

__global__ __launch_bounds__(256) void qkv_gemm(
    const ushort_t* __restrict__ A, const ushort_t* __restrict__ B,
    const float* __restrict__ bias,
    ushort_t* __restrict__ Qb, ushort_t* __restrict__ Kb, ushort_t* __restrict__ Vtb,
    const float* __restrict__ coords, const float* __restrict__ elev,
    const float* __restrict__ alpha_p, unsigned* __restrict__ pack,
    const float* __restrict__ pw, ushort_t* __restrict__ pwb)
{
    // dbuf layout (ushort idx): As(b) @ b*16384, Bs(b) @ b*16384 + 8192
    __shared__ __align__(16) ushort_t SM[32768];
    const int t = threadIdx.x;

    if (blockIdx.x >= QKV_BLOCKS + PACK_BLOCKS) {
        // ---- proj_w conversion tail ----
        const unsigned i = (blockIdx.x - QKV_BLOCKS - PACK_BLOCKS) * 256 + t;
        if (i >= PWB_N / 8) return;
        const float4 a = ((const float4*)pw)[i * 2];
        const float4 b = ((const float4*)pw)[i * 2 + 1];
        uint4 pk;
        pk.x = pk2(a.x, a.y); pk.y = pk2(a.z, a.w);
        pk.z = pk2(b.x, b.y); pk.w = pk2(b.z, b.w);
        ((uint4*)pwb)[i] = pk;
        return;
    }
    if (blockIdx.x >= QKV_BLOCKS) {
        // ---- bias-pack half (LUT in SM bytes) ----
        unsigned char* LUT = (unsigned char*)SM;
        LUT[t] = (unsigned char)bucketf(t - 128);
        if (t == 0) LUT[256] = (unsigned char)bucketf(128);
        __syncthreads();

        const int blk = blockIdx.x - QKV_BLOCKS;
        const int b = blk >> 10, i = blk & 1023;
        const float alpha = alpha_p[0];
        const float2 ci = *(const float2*)&coords[(size_t)(b * NSEQ + i) * 2];
        const int cxi = (int)(ci.x * 128.0f), cyi = (int)(ci.y * 128.0f);
        const float ei = elev[b * NSEQ + i];
        const int j0 = t * 4;
        const float4 c01 = *(const float4*)&coords[(size_t)(b * NSEQ + j0) * 2];
        const float4 c23 = *(const float4*)&coords[(size_t)(b * NSEQ + j0 + 2) * 2];
        const float4 ej4 = *(const float4*)&elev[b * NSEQ + j0];
        const float cjx[4] = {c01.x, c01.z, c23.x, c23.z};
        const float cjy[4] = {c01.y, c01.w, c23.y, c23.w};
        const float ejv[4] = {ej4.x, ej4.y, ej4.z, ej4.w};
        unsigned r[4];
        #pragma unroll
        for (int k = 0; k < 4; ++k) {
            const int dx = cxi - (int)(cjx[k] * 128.0f);
            const int dy = cyi - (int)(cjy[k] * 128.0f);
            const int idx = ((int)LUT[dx + 128] << 5) | (int)LUT[dy + 128];
            const float ed = (ejv[k] - ei) * 1e-3f;
            const float eb = fmaxf(-alpha * fmaxf(ed, 0.0f), -10.0f) * LOG2E;
            r[k] = ((unsigned)f2bf(eb) << 16) | (unsigned)idx;
        }
        uint4 o; o.x = r[0]; o.y = r[1]; o.z = r[2]; o.w = r[3];
        *(uint4*)&pack[((size_t)b << 20) + (size_t)i * NSEQ + j0] = o;
        return;
    }

    // ---- GEMM half ----
    // XCD swizzle: 576 = 8 XCDs x 72; each XCD owns 4 complete M-panels.
    const int lid = (blockIdx.x & 7) * 72 + (blockIdx.x >> 3);
    const int bx = lid % 18, by = lid / 18;
    const int m0 = by * 128, c0 = bx * 128;

    const int lane = t & 63, w = t >> 6;
    const int wr = w >> 1, wc = w & 1;            // wave quadrant: 64M x 64N
    const int col = lane & 15, quad = lane >> 4;
    const int c7 = col & 7;

    const f32x4 zero = {0.f, 0.f, 0.f, 0.f};
    f32x4 acc[4][4];
    #pragma unroll
    for (int i = 0; i < 4; ++i)
        #pragma unroll
        for (int j = 0; j < 4; ++j) acc[i][j] = zero;

    // staging: wave w stages rows w*32..w*32+31 of A and B (4 gl_lds each).
    // source col pre-swizzled so LDS (row, g) holds global group g^(row&7).
    const int r8 = lane >> 3, g8 = lane & 7;
    const int gsw = ((g8 ^ r8) * 8);
    const ushort_t* Ag = A + (size_t)(m0 + w * 32 + r8) * DMODEL + gsw;
    const ushort_t* Bg = B + (size_t)(c0 + w * 32 + r8) * DMODEL + gsw;
    const int wso = (w * 32) * 64;                // wave staging offset in buf

    auto STAGE = [&](int bo, int k0) {
        ushort_t* Aw = SM + bo + wso;
        ushort_t* Bw = SM + bo + 8192 + wso;
        gl_lds16(Ag + k0, Aw);
        gl_lds16(Ag + (size_t)8 * DMODEL + k0, Aw + 8 * 64);
        gl_lds16(Ag + (size_t)16 * DMODEL + k0, Aw + 16 * 64);
        gl_lds16(Ag + (size_t)24 * DMODEL + k0, Aw + 24 * 64);
        gl_lds16(Bg + k0, Bw);
        gl_lds16(Bg + (size_t)8 * DMODEL + k0, Bw + 8 * 64);
        gl_lds16(Bg + (size_t)16 * DMODEL + k0, Bw + 16 * 64);
        gl_lds16(Bg + (size_t)24 * DMODEL + k0, Bw + 24 * 64);
    };

    STAGE(0, 0);
    __syncthreads();   // prologue drain: buf0 ready

    #pragma unroll 2
    for (int k = 0; k < 12; ++k) {
        const int bo = (k & 1) * 16384;
        if (k < 11) STAGE(16384 - bo, (k + 1) * 64);   // issue next (no wait)
        #pragma unroll
        for (int kk = 0; kk < 2; ++kk) {
            bf16x8 af[4], bf[4];
            #pragma unroll
            for (int im = 0; im < 4; ++im)
                af[im] = *(const bf16x8*)&SM[bo + (wr * 64 + im * 16 + col) * 64
                        + ((4 * kk + quad) ^ c7) * 8];
            #pragma unroll
            for (int jn = 0; jn < 4; ++jn)
                bf[jn] = *(const bf16x8*)&SM[bo + 8192 + (wc * 64 + jn * 16 + col) * 64
                        + ((4 * kk + quad) ^ c7) * 8];
            #pragma unroll
            for (int im = 0; im < 4; ++im)
                #pragma unroll
                for (int jn = 0; jn < 4; ++jn)
                    acc[im][jn] = __builtin_amdgcn_mfma_f32_16x16x32_bf16(af[im], bf[jn], acc[im][jn], 0, 0, 0);
        }
        __syncthreads();   // ONE barrier/step; vmcnt drain lands after compute
    }

    const int cbw = c0 + wc * 64;                 // wave's 64-col base = one head
    const int s = cbw / DMODEL;                   // wave-uniform
    const int h = (cbw % DMODEL) >> 6;
    const int b = m0 >> 10;
    const int bh = b * NH + h;
    const int n0 = (m0 & (NSEQ - 1)) + wr * 64;

    float bv[4];
    #pragma unroll
    for (int jn = 0; jn < 4; ++jn) bv[jn] = bias[cbw + jn * 16 + col];

    if (s < 2) {
        // LDS transpose epilogue: per im-block the wave writes a 16x64 bf16
        // tile (stride 72), reads rows back, stores 2 coalesced uint4/lane.
        ushort_t* lt = SM + w * 1152;             // 16 rows x 72
        ushort_t* dst = (s == 0) ? Qb : Kb;
        const float sc = (s == 0) ? 0.125f * LOG2E : 1.0f;
        const int row16 = lane >> 2, seg = lane & 3;
        #pragma unroll
        for (int im = 0; im < 4; ++im) {
            #pragma unroll
            for (int jn = 0; jn < 4; ++jn) {
                const f32x4 a = acc[im][jn];
                #pragma unroll
                for (int r = 0; r < 4; ++r)
                    lt[(quad * 4 + r) * 72 + jn * 16 + col] = f2bf((a[r] + bv[jn]) * sc);
            }
            // same-wave DS is in-order: reads below see the writes above
            const uint4 u0 = *(const uint4*)&lt[row16 * 72 + seg * 8];
            const uint4 u1 = *(const uint4*)&lt[row16 * 72 + 32 + seg * 8];
            const size_t gb = ((size_t)bh * NSEQ + n0 + im * 16 + row16) * HD
                            + seg * 8;
            *(uint4*)&dst[gb] = u0;
            *(uint4*)&dst[gb + 32] = u1;
        }
    } else {
        #pragma unroll
        for (int im = 0; im < 4; ++im) {
            #pragma unroll
            for (int jn = 0; jn < 4; ++jn) {
                const int d = jn * 16 + col;
                const float bvv = bv[jn];
                const f32x4 a = acc[im][jn];
                uint2 p;
                p.x = pk2(a[0] + bvv, a[1] + bvv);
                p.y = pk2(a[2] + bvv, a[3] + bvv);
                *(uint2*)&Vtb[((size_t)bh * HD + d) * NSEQ + n0 + im * 16 + quad * 4] = p;
            }
        }
    }
}

// ---------------------------------------------------------------------------
// Fused flash attention (R11/R12 best, reverted after R13 regression):
// 256 thr / 4 waves / 64 Q-rows; gl_lds swizzled K/V staging, raw v_exp
// softmax, f32 bias table, bias prefetch pipeline, setprio, XCD swizzle.
// ---------------------------------------------------------------------------
#define RBIAS32(u) (tabu32[(u) & 1023u] + __uint_as_float((u) & 0xFFFF0000u))

__global__ __launch_bounds__(256) void attn_mfma(
    const ushort_t* __restrict__ Qb, const ushort_t* __restrict__ Kb,
    const ushort_t* __restrict__ Vtb,
    const unsigned* __restrict__ pack,
    const float* __restrict__ table,
    ushort_t* __restrict__ Ob)
{
    __shared__ __align__(16) ushort_t Ks[2][64 * 64];
    __shared__ __align__(16) ushort_t Vt[2][64 * 64];
    __shared__ __align__(16) ushort_t Ps[64 * 72];
    __shared__ float tabu32[1024];   // table[:,h] * log2e (f32)

    const int t = threadIdx.x;
    const int lane = t & 63, w = t >> 6;
    const int col = lane & 15, quad = lane >> 4;
    const int c7 = col & 7;
    const int bid = (blockIdx.x & 7) * 96 + (blockIdx.x >> 3);   // XCD swizzle
    const int it = bid & 15, bh = bid >> 4;
    const int h = bh % NH, b = bh / NH;
    const int i0 = it * 64;

    for (int i = t; i < 1024; i += 256)
        tabu32[i] = table[i * NH + h] * LOG2E;

    const ushort_t* Qg = Qb + ((size_t)bh * NSEQ + i0 + w * 16 + col) * HD;
    const bf16x8 aq0 = *(const bf16x8*)(Qg + quad * 8);
    const bf16x8 aq1 = *(const bf16x8*)(Qg + 32 + quad * 8);

    const size_t kvbase = (size_t)bh * NSEQ * HD;
    const unsigned* prow = pack + ((size_t)b << 20)
                         + (size_t)(i0 + w * 16 + col) * NSEQ + quad * 4;

    // gl_lds staging: wave w stages rows 16w..16w+15 of K and of V^T
    // (2 gl_lds each, 8 rows per issue). Source group pre-swizzled by
    // lg^lr so LDS (row, pos) holds global group pos^(row&7).
    const int lr = lane >> 3, lg = lane & 7;
    const int swz = (lg ^ lr) * 8;
    const int row0 = 16 * w + lr;                 // rows row0, row0+8
    const ushort_t* Kg = Kb + kvbase + (size_t)row0 * HD + swz;
    const ushort_t* Vg = Vtb + kvbase + (size_t)row0 * NSEQ + swz;
    const int kvso = (16 * w) * 64;               // wave LDS base (ushorts)

    auto STAGE_KV = [&](int buf, int j0) {
        gl_lds16(Kg + (size_t)j0 * HD, &Ks[buf][kvso]);
        gl_lds16(Kg + (size_t)(j0 + 8) * HD, &Ks[buf][kvso + 8 * 64]);
        gl_lds16(Vg + j0, &Vt[buf][kvso]);
        gl_lds16(Vg + (size_t)8 * NSEQ + j0, &Vt[buf][kvso + 8 * 64]);
    };

    STAGE_KV(0, 0);

    // bias pipeline: pk4g = pack words for the tile to gather next;
    // pk4l = loads in flight two tiles ahead; rbc = bias for current tile.
    uint4 pk4g[4], pk4l[4];
    #pragma unroll
    for (int jb = 0; jb < 4; ++jb)
        pk4g[jb] = *(const uint4*)(prow + jb * 16);

    __syncthreads();   // drains tabu32 writes AND the buf0 DMA

    float rbc[4][4], rbn[4][4];
    #pragma unroll
    for (int jb = 0; jb < 4; ++jb) {
        const uint4 pkv = pk4g[jb];
        rbc[jb][0] = RBIAS32(pkv.x);
        rbc[jb][1] = RBIAS32(pkv.y);
        rbc[jb][2] = RBIAS32(pkv.z);
        rbc[jb][3] = RBIAS32(pkv.w);
    }
    #pragma unroll
    for (int jb = 0; jb < 4; ++jb)
        pk4g[jb] = *(const uint4*)(prow + 64 + jb * 16);

    const f32x4 zero = {0.f, 0.f, 0.f, 0.f};
    f32x4 o_acc[4];
    #pragma unroll
    for (int i = 0; i < 4; ++i) o_acc[i] = zero;
    float l_l = 0.f;

    const int kx = (quad ^ c7) * 8;               // swizzled group offset

    #pragma unroll 2
    for (int jt = 0; jt < 16; ++jt) {
        if (jt) __syncthreads();   // buf[cur] DMA drained; buf[cur^1] reads done
        const int cur = jt & 1;

        if (jt < 15) STAGE_KV(cur ^ 1, (jt + 1) * 64);   // DMA next tile
        if (jt < 14) {
            const int j2 = (jt + 2) * 64;
            #pragma unroll
            for (int jb = 0; jb < 4; ++jb)
                pk4l[jb] = *(const uint4*)(prow + j2 + jb * 16);
        }

        // S^T = K Q^T  (swizzled fragment reads: group g at pos g^(row&7))
        f32x4 sacc[4];
        __builtin_amdgcn_s_setprio(1);
        #pragma unroll
        for (int jb = 0; jb < 4; ++jb) {
            sacc[jb] = zero;
            const bf16x8 kb0 = *(const bf16x8*)&Ks[cur][(jb * 16 + col) * 64 + kx];
            const bf16x8 kb1 = *(const bf16x8*)&Ks[cur][(jb * 16 + col) * 64 + (kx ^ 32)];
            sacc[jb] = __builtin_amdgcn_mfma_f32_16x16x32_bf16(kb0, aq0, sacc[jb], 0, 0, 0);
            sacc[jb] = __builtin_amdgcn_mfma_f32_16x16x32_bf16(kb1, aq1, sacc[jb], 0, 0, 0);
        }
        __builtin_amdgcn_s_setprio(0);

        // fixed-m softmax with PREFETCHED bias: p = exp2(s + rbc), raw v_exp
        float psum = 0.f;
        #pragma unroll
        for (int jb = 0; jb < 4; ++jb) {
            const float p0 = EXP2R(sacc[jb][0] + rbc[jb][0]);
            const float p1 = EXP2R(sacc[jb][1] + rbc[jb][1]);
            const float p2 = EXP2R(sacc[jb][2] + rbc[jb][2]);
            const float p3 = EXP2R(sacc[jb][3] + rbc[jb][3]);
            psum += (p0 + p1) + (p2 + p3);
            uint2 st;
            st.x = pk2(p0, p1);
            st.y = pk2(p2, p3);
            *(uint2*)&Ps[(w * 16 + col) * 72 + jb * 16 + quad * 4] = st;
        }
        l_l += psum;

        // O += P V; next-tile bias gathers interleaved with the PV MFMAs
        const bf16x8 ap0 = *(const bf16x8*)&Ps[(w * 16 + col) * 72 + quad * 8];
        const bf16x8 ap1 = *(const bf16x8*)&Ps[(w * 16 + col) * 72 + 32 + quad * 8];
        __builtin_amdgcn_s_setprio(1);
        #pragma unroll
        for (int db = 0; db < 4; ++db) {
            const bf16x8 vv0 = *(const bf16x8*)&Vt[cur][(db * 16 + col) * 64 + kx];
            const bf16x8 vv1 = *(const bf16x8*)&Vt[cur][(db * 16 + col) * 64 + (kx ^ 32)];
            o_acc[db] = __builtin_amdgcn_mfma_f32_16x16x32_bf16(ap0, vv0, o_acc[db], 0, 0, 0);
            o_acc[db] = __builtin_amdgcn_mfma_f32_16x16x32_bf16(ap1, vv1, o_acc[db], 0, 0, 0);
            if (jt < 15) {
                const uint4 pkv = pk4g[db];
                rbn[db][0] = RBIAS32(pkv.x);
                rbn[db][1] = RBIAS32(pkv.y);
                rbn[db][2] = RBIAS32(pkv.z);
                rbn[db][3] = RBIAS32(pkv.w);
            }
        }
        __builtin_amdgcn_s_setprio(0);

        // rotate pipeline regs (renamed away by the unroll)
        #pragma unroll
        for (int jb = 0; jb < 4; ++jb) {
            pk4g[jb] = pk4l[jb];
            rbc[jb][0] = rbn[jb][0];
            rbc[jb][1] = rbn[jb][1];
            rbc[jb][2] = rbn[jb][2];
            rbc[jb][3] = rbn[jb][3];
        }
    }

    // epilogue: reduce l over quads, normalize, store bf16
    float l = l_l;
    l += __shfl_xor(l, 16);
    l += __shfl_xor(l, 32);
    #pragma unroll
    for (int r = 0; r < 4; ++r) {
        const float lr2 = __shfl(l, w * 16 + quad * 4 + r);
        const float inv = 1.f / lr2;
        const int ri = w * 16 + quad * 4 + r;
        const size_t base = ((size_t)(b * NSEQ) + i0 + ri) * DMODEL + h * HD;
        #pragma unroll
        for (int db = 0; db < 4; ++db)
            Ob[base + db * 16 + col] = f2bf(o_acc[db][r] * inv);
    }
}

// ---------------------------------------------------------------------------
// Proj GEMM (R8 structure, unchanged): 64x64 tiles, BK=64, 2-phase dbuf.
// ---------------------------------------------------------------------------
__global__ __launch_bounds__(256) void proj_gemm(
    const ushort_t* __restrict__ A, const ushort_t* __restrict__ B,
    const float* __restrict__ bias, float* __restrict__ out)
{
    // dbuf layout (ushort idx): As(b) @ b*8192, Bs(b) @ b*8192 + 4096
    __shared__ __align__(16) ushort_t SM[16384];
    const int t = threadIdx.x;
    const int lane = t & 63, w = t >> 6;
    const int wr = w >> 1, wc = w & 1;
    const int col = lane & 15, quad = lane >> 4;
    const int c7 = col & 7;
    const int m0 = blockIdx.y * 64, c0 = blockIdx.x * 64;

    const f32x4 zero = {0.f, 0.f, 0.f, 0.f};
    f32x4 acc[2][2];
    #pragma unroll
    for (int i = 0; i < 2; ++i)
        #pragma unroll
        for (int j = 0; j < 2; ++j) acc[i][j] = zero;

    const int r8 = lane >> 3, g8 = lane & 7;
    const int gsw = ((g8 ^ r8) * 8);
    const ushort_t* Ag = A + (size_t)(m0 + w * 16 + r8) * DMODEL + gsw;
    const ushort_t* Bg = B + (size_t)(c0 + w * 16 + r8) * DMODEL + gsw;
    const int wso = (w * 16) * 64;

    auto STAGE = [&](int bo, int k0) {
        ushort_t* Aw = SM + bo + wso;
        ushort_t* Bw = SM + bo + 4096 + wso;
        gl_lds16(Ag + k0, Aw);
        gl_lds16(Ag + (size_t)8 * DMODEL + k0, Aw + 8 * 64);
        gl_lds16(Bg + k0, Bw);
        gl_lds16(Bg + (size_t)8 * DMODEL + k0, Bw + 8 * 64);
    };

    STAGE(0, 0);
    __syncthreads();

    #pragma unroll 2
    for (int k = 0; k < 12; ++k) {
        const int bo = (k & 1) * 8192;
        if (k < 11) STAGE(8192 - bo, (k + 1) * 64);
        #pragma unroll
        for (int kk = 0; kk < 2; ++kk) {
            bf16x8 af[2], bf[2];
            #pragma unroll
            for (int im = 0; im < 2; ++im)
                af[im] = *(const bf16x8*)&SM[bo + (wr * 32 + im * 16 + col) * 64
                        + ((4 * kk + quad) ^ c7) * 8];
            #pragma unroll
            for (int jn = 0; jn < 2; ++jn)
                bf[jn] = *(const bf16x8*)&SM[bo + 4096 + (wc * 32 + jn * 16 + col) * 64
                        + ((4 * kk + quad) ^ c7) * 8];
            #pragma unroll
            for (int im = 0; im < 2; ++im)
                #pragma unroll
                for (int jn = 0; jn < 2; ++jn)
                    acc[im][jn] = __builtin_amdgcn_mfma_f32_16x16x32_bf16(af[im], bf[jn], acc[im][jn], 0, 0, 0);
        }
        __syncthreads();
    }

    #pragma unroll
    for (int im = 0; im < 2; ++im) {
        #pragma unroll
        for (int jn = 0; jn < 2; ++jn) {
            const int c = c0 + wc * 32 + jn * 16 + col;
            const float bv = bias[c];
            #pragma unroll
            for (int r = 0; r < 4; ++r) {
                const int m = m0 + wr * 32 + im * 16 + quad * 4 + r;
                out[(size_t)m * DMODEL + c] = acc[im][jn][r] + bv;
            }
        }
    }
}

extern "C" void kernel_launch(void* const* d_in, const int* in_sizes, int n_in,
                              void* d_out, int out_size, void* d_ws, size_t ws_size,
                              hipStream_t stream) {
    const float* x       = (const float*)d_in[0];
    const float* coords  = (const float*)d_in[1];
    const float* elev    = (const float*)d_in[2];
    const float* qkv_w   = (const float*)d_in[3];
    const float* qkv_b   = (const float*)d_in[4];
    const float* proj_w  = (const float*)d_in[5];
    const float* proj_b  = (const float*)d_in[6];
    const float* btable  = (const float*)d_in[7];
    const float* alpha   = (const float*)d_in[8];
    float* out = (float*)d_out;

    ushort_t* wsu = (ushort_t*)d_ws;
    ushort_t* xb  = wsu;
    ushort_t* wqb = wsu + 3145728;
    ushort_t* pwb = wsu + 4915200;
    ushort_t* Qb  = wsu + 5505024;
    ushort_t* Kb  = wsu + 8650752;
    ushort_t* Vtb = wsu + 11796480;
    ushort_t* Ob  = wsu + 14942208;
    unsigned* pck = (unsigned*)(wsu + 18087936);   // 4M uint32 = 16 MB

    prep_kernel<<<CVT_BLOCKS, 256, 0, stream>>>(x, qkv_w, wsu);
    qkv_gemm<<<QKV_BLOCKS + PACK_BLOCKS + PW_BLOCKS, 256, 0, stream>>>(
        xb, wqb, qkv_b, Qb, Kb, Vtb, coords, elev, alpha, pck, proj_w, pwb);
    attn_mfma<<<768, 256, 0, stream>>>(Qb, Kb, Vtb, pck, btable, Ob);
    proj_gemm<<<dim3(12, 64), 256, 0, stream>>>(Ob, pwb, proj_b, out);
}